// Round 1
// baseline (585.668 us; speedup 1.0000x reference)
//
#include <hip/hip_runtime.h>

#define N_  8
#define C_  32
#define H_  224
#define W_  224
#define TM_ 4

// One thread per (t, c, a, b); loops over n (batch) with transform reuse.
// Output layout: out[n, c*TM + t, a, b]  (from reference's transpose(0,2,1,3,4)).
// Reference quirk: hx = xs[a], hy = ys[b]  (meshgrid 'ij' + reshape, H==W).
__global__ __launch_bounds__(256) void persp_kernel(
    const float* __restrict__ inp,   // (N, C, H, W)
    const float* __restrict__ wt,    // (TM, C, 8)
    float* __restrict__ out)         // (N, C*TM, H, W)
{
    const int idx = blockIdx.x * 256 + threadIdx.x;
    // total = TM_*C_*H_*W_ = 6,422,528 ; grid sized exactly, no tail check needed
    const int b = idx % W_;
    const int a = (idx / W_) % H_;
    const int c = (idx / (W_ * H_)) % C_;
    const int t = idx / (W_ * H_ * C_);

    const float* th = wt + ((size_t)t * C_ + c) * 8;
    const float t0 = th[0], t1 = th[1], t2 = th[2], t3 = th[3];
    const float t4 = th[4], t5 = th[5], t6 = th[6], t7 = th[7];

    const float step = 2.0f / 223.0f;           // linspace(-1,1,224) step
    const float hx = -1.0f + (float)a * step;   // xs[a]
    const float hy = -1.0f + (float)b * step;   // ys[b]

    const float w0 = t0 * hx + t1 * hy + t2;
    const float w1 = t3 * hx + t4 * hy + t5;
    const float w2 = t6 * hx + t7 * hy + 1.0f;

    const float xs = w0 / w2;
    const float ys = w1 / w2;

    // x = 0.5*((x_s+1)*(max_x-1)), max_x = 223 -> scale 222
    const float x = 0.5f * ((xs + 1.0f) * 222.0f);
    const float y = 0.5f * ((ys + 1.0f) * 222.0f);

    const float fx = floorf(x);
    const float fy = floorf(y);
    int x0 = (int)fx;
    int y0 = (int)fy;
    int x1 = x0 + 1;
    int y1 = y0 + 1;
    x0 = min(max(x0, 0), W_ - 1);
    x1 = min(max(x1, 0), W_ - 1);
    y0 = min(max(y0, 0), H_ - 1);
    y1 = min(max(y1, 0), H_ - 1);

    const float x0f = (float)x0, x1f = (float)x1;
    const float y0f = (float)y0, y1f = (float)y1;

    const float wa = (x1f - x) * (y1f - y);
    const float wb = (x1f - x) * (y1f - y0f);
    const float wc = (x - x0f) * (y1f - y);
    const float wd = (x - x0f) * (y - y0f);

    const int iA = y0 * W_ + x0;
    const int iB = y1 * W_ + x0;
    const int iC = y0 * W_ + x1;
    const int iD = y1 * W_ + x1;

    const float* ibase = inp + (size_t)c * (H_ * W_);
    float* obase = out + ((size_t)(c * TM_ + t)) * (H_ * W_) + (size_t)a * W_ + b;
    const size_t istride = (size_t)C_ * H_ * W_;
    const size_t ostride = (size_t)(C_ * TM_) * H_ * W_;

#pragma unroll
    for (int n = 0; n < N_; ++n) {
        const float Ia = ibase[iA];
        const float Ib = ibase[iB];
        const float Ic = ibase[iC];
        const float Id = ibase[iD];
        *obase = wa * Ia + wb * Ib + wc * Ic + wd * Id;
        ibase += istride;
        obase += ostride;
    }
}

extern "C" void kernel_launch(void* const* d_in, const int* in_sizes, int n_in,
                              void* d_out, int out_size, void* d_ws, size_t ws_size,
                              hipStream_t stream) {
    const float* inp = (const float*)d_in[0];   // (8,32,224,224) f32
    const float* wt  = (const float*)d_in[1];   // (4,32,8) f32
    float* out = (float*)d_out;                 // (8,128,224,224) f32

    const int total  = TM_ * C_ * H_ * W_;      // 6,422,528
    const int blocks = total / 256;             // 25088, exact
    persp_kernel<<<blocks, 256, 0, stream>>>(inp, wt, out);
}

// Round 2
// 343.737 us; speedup vs baseline: 1.7038x; 1.7038x over previous
//
#include <hip/hip_runtime.h>

#define N_  8
#define C_  32
#define H_  224
#define W_  224
#define TM_ 4
#define TA  32   // output tile extent along a (rows)
#define TB  32   // output tile extent along b (cols)

// Block = 256 threads handles one (c, 32x32 output tile) for ALL t (4) and n (8).
// Compute phase: lanes along a  -> sample x consecutive per lane -> coalesced gathers.
// Write  phase: lanes along b  -> coalesced stores (via LDS transpose tile).
// Reference quirk preserved: hx = xs[a], hy = ys[b]; out channel = c*TM + t.
__global__ __launch_bounds__(256) void persp_kernel(
    const float* __restrict__ inp,   // (N, C, H, W)
    const float* __restrict__ wt,    // (TM, C, 8)
    float* __restrict__ out)         // (N, C*TM, H, W)
{
    __shared__ float tile[N_][TA][TB + 1];   // +1 pad: conflict-free transpose

    const int tid = threadIdx.x;
    const int c   = blockIdx.y;
    const int ta  = blockIdx.x / (W_ / TB);
    const int tb  = blockIdx.x % (W_ / TB);
    const int a0  = ta * TA;
    const int b0  = tb * TB;

    // compute-phase mapping: lane -> a, group -> b
    const int a_off = tid & 31;        // 0..31 along a (fast, per half-wave)
    const int bgrp  = tid >> 5;        // 0..7
    const int a     = a0 + a_off;

    const float step = 2.0f / 223.0f;  // linspace(-1,1,224) step
    const float hx   = -1.0f + (float)a * step;   // xs[a]

    // write-phase mapping: lane -> b (j), group -> a rows (i0 + 8k)
    const int j  = tid & 31;
    const int i0 = tid >> 5;

    const size_t plane   = (size_t)H_ * W_;
    const size_t istride = (size_t)C_ * plane;         // per-n input stride
    const size_t ostride = (size_t)(C_ * TM_) * plane; // per-n output stride

    for (int t = 0; t < TM_; ++t) {
        const float* th = wt + ((size_t)t * C_ + c) * 8;
        const float t0 = th[0], t1 = th[1], t2 = th[2], t3 = th[3];
        const float t4 = th[4], t5 = th[5], t6 = th[6], t7 = th[7];

        int   iA[4], iB[4], iC[4], iD[4];
        float wa[4], wb[4], wc[4], wd[4];

#pragma unroll
        for (int p = 0; p < 4; ++p) {
            const int b = b0 + bgrp + 8 * p;
            const float hy = -1.0f + (float)b * step;  // ys[b]

            const float w0 = t0 * hx + t1 * hy + t2;
            const float w1 = t3 * hx + t4 * hy + t5;
            const float w2 = t6 * hx + t7 * hy + 1.0f;

            const float xs = w0 / w2;
            const float ys = w1 / w2;

            const float x = 0.5f * ((xs + 1.0f) * 222.0f);
            const float y = 0.5f * ((ys + 1.0f) * 222.0f);

            int x0i = (int)floorf(x);
            int y0i = (int)floorf(y);
            int x1i = x0i + 1;
            int y1i = y0i + 1;
            x0i = min(max(x0i, 0), W_ - 1);
            x1i = min(max(x1i, 0), W_ - 1);
            y0i = min(max(y0i, 0), H_ - 1);
            y1i = min(max(y1i, 0), H_ - 1);

            const float x0f = (float)x0i, x1f = (float)x1i;
            const float y0f = (float)y0i, y1f = (float)y1i;

            wa[p] = (x1f - x) * (y1f - y);
            wb[p] = (x1f - x) * (y1f - y0f);
            wc[p] = (x - x0f) * (y1f - y);
            wd[p] = (x - x0f) * (y - y0f);

            iA[p] = y0i * W_ + x0i;
            iB[p] = y1i * W_ + x0i;
            iC[p] = y0i * W_ + x1i;
            iD[p] = y1i * W_ + x1i;
        }

#pragma unroll
        for (int n = 0; n < N_; ++n) {
            const float* ib = inp + (size_t)n * istride + (size_t)c * plane;
#pragma unroll
            for (int p = 0; p < 4; ++p) {
                const float Ia = ib[iA[p]];
                const float Ib = ib[iB[p]];
                const float Ic = ib[iC[p]];
                const float Id = ib[iD[p]];
                tile[n][a_off][bgrp + 8 * p] =
                    wa[p] * Ia + wb[p] * Ib + wc[p] * Ic + wd[p] * Id;
            }
        }
        __syncthreads();

        // coalesced write-out: lanes along b
        float* ob = out + ((size_t)(c * TM_ + t)) * plane + (size_t)a0 * W_ + b0;
#pragma unroll
        for (int n = 0; n < N_; ++n) {
            float* obn = ob + (size_t)n * ostride;
#pragma unroll
            for (int k = 0; k < 4; ++k) {
                const int i = i0 + 8 * k;
                obn[(size_t)i * W_ + j] = tile[n][i][j];
            }
        }
        __syncthreads();
    }
}

extern "C" void kernel_launch(void* const* d_in, const int* in_sizes, int n_in,
                              void* d_out, int out_size, void* d_ws, size_t ws_size,
                              hipStream_t stream) {
    const float* inp = (const float*)d_in[0];   // (8,32,224,224) f32
    const float* wt  = (const float*)d_in[1];   // (4,32,8) f32
    float* out = (float*)d_out;                 // (8,128,224,224) f32

    dim3 grid((H_ / TA) * (W_ / TB), C_);       // 49 x 32 = 1568 blocks
    persp_kernel<<<grid, 256, 0, stream>>>(inp, wt, out);
}